// Round 9
// baseline (4907.959 us; speedup 1.0000x reference)
//
#include <hip/hip_runtime.h>
#include <hip/hip_fp16.h>
#include <math.h>

// ---------------------------------------------------------------------------
// GCN: 3x (GCNConv -> BatchNorm -> ReLU) -> fc1+ReLU -> fc2 -> log_softmax
// N=100000, E=1600000, IN=128, HID=64, classes=2.
// SINGLE persistent mega-kernel: CSR build + 3x(MFMA gemm -> gather+stats) +
// head, separated by device-wide barriers (device-scope atomics + fences).
// Co-residency by construction: 1024 blocks x 256 thr, VGPR<=128
// (__launch_bounds__(256,4) -> 16 waves/CU), LDS 34.8KB -> 4 blocks/CU exact.
// Poison-proof init: MAGIC gate (block0 zeroes ctrl/gcur/stats, releases gate;
// gate reset to 0 at end; 0xAA poison != MAGIC).
// ---------------------------------------------------------------------------

#define NBLK 1024
#define NTHR 256
#define BUCK_CAP 6144
#define PART_CHUNK 4096
#define MAGIC 0x7E57C0DE

typedef _Float16 f16x8 __attribute__((ext_vector_type(8)));
typedef float f32x4 __attribute__((ext_vector_type(4)));

union H4U { uint2 u; __half h[4]; };
union H8U { uint4 u; __half h[8]; };

__device__ inline uint2 pack4(float a, float b, float c, float d) {
    H4U t;
    t.h[0] = __float2half_rn(a); t.h[1] = __float2half_rn(b);
    t.h[2] = __float2half_rn(c); t.h[3] = __float2half_rn(d);
    return t.u;
}
__device__ inline float4 unpack4(uint2 u) {
    H4U t; t.u = u;
    return make_float4(__half2float(t.h[0]), __half2float(t.h[1]),
                       __half2float(t.h[2]), __half2float(t.h[3]));
}
__device__ inline void upadd8(uint4 u, float* a) {
    H8U t; t.u = u;
#pragma unroll
    for (int i = 0; i < 8; ++i) a[i] += __half2float(t.h[i]);
}

// Device-wide barrier: slot used once per call. All NBLK blocks must arrive.
__device__ __forceinline__ void gbar(int* cnt, int idx) {
    __syncthreads();
    if (threadIdx.x == 0) {
        __threadfence();  // release: drain this block's writes to coherence pt
        __hip_atomic_fetch_add(&cnt[idx], 1, __ATOMIC_ACQ_REL,
                               __HIP_MEMORY_SCOPE_AGENT);
        while (__hip_atomic_fetch_add(&cnt[idx], 0, __ATOMIC_ACQ_REL,
                                      __HIP_MEMORY_SCOPE_AGENT) < NBLK)
            __builtin_amdgcn_s_sleep(16);
        __threadfence();  // acquire: invalidate this CU's stale cached lines
    }
    __syncthreads();
}

// ---- Phase: bucket partition (bucket = dst>>8), 4096-edge chunks ----------
__device__ void ph_part(char* sm, const int* __restrict__ src,
                        const int* __restrict__ dst, int* __restrict__ gcur,
                        unsigned* __restrict__ rec, int E, int NB) {
    int* hist = (int*)sm;        // 512 ints
    int* gbase = hist + 512;     // 512 ints
    const int tid = threadIdx.x;
    for (int chunk = blockIdx.x; chunk * PART_CHUNK < E; chunk += gridDim.x) {
        const int e0 = chunk * PART_CHUNK;
        const int e1 = min(e0 + PART_CHUNK, E);
        hist[tid] = 0; hist[tid + 256] = 0;
        __syncthreads();
        for (int i = e0 + tid; i < e1; i += 256)
            atomicAdd(&hist[dst[i] >> 8], 1);
        __syncthreads();
        for (int b = tid; b < NB; b += 256) {
            int c = hist[b];
            gbase[b] = c ? atomicAdd(&gcur[b], c) : 0;
            hist[b] = 0;  // reuse as cursor
        }
        __syncthreads();
        for (int i = e0 + tid; i < e1; i += 256) {
            int d = dst[i], s = src[i];
            int b = d >> 8;
            int off = atomicAdd(&hist[b], 1);
            rec[(size_t)b * BUCK_CAP + gbase[b] + off] =
                ((unsigned)s << 8) | (unsigned)(d & 255);
        }
        __syncthreads();
    }
}

// ---- Phase: per-bucket hist+scan+scatter -> dis, row_ptr, ssrc ------------
__device__ void ph_bscat(char* sm, const int* __restrict__ gcur,
                         const unsigned* __restrict__ rec,
                         float* __restrict__ dis, int* __restrict__ row_ptr,
                         int* __restrict__ ssrc, int n, int NB, int E) {
    if ((int)blockIdx.x >= NB) return;  // no barriers inside: safe
    int* h     = (int*)sm;        // 256
    int* cur   = h + 256;         // 256
    int* lb    = cur + 256;       // 512
    int* stmp  = lb + 512;        // 256
    int* stage = stmp + 256;      // 6144 (24 KB)
    const int b = blockIdx.x, tid = threadIdx.x;
    int g0 = (2 * tid < NB) ? gcur[2 * tid] : 0;
    int g1 = (2 * tid + 1 < NB) ? gcur[2 * tid + 1] : 0;
    int ps = g0 + g1;
    stmp[tid] = ps;
    h[tid] = 0;
    __syncthreads();
    int xx = ps;
    for (int off = 1; off < 256; off <<= 1) {
        int y = (tid >= off) ? stmp[tid - off] : 0;
        __syncthreads();
        xx += y;
        stmp[tid] = xx;
        __syncthreads();
    }
    int ex = xx - ps;
    lb[2 * tid] = ex;
    lb[2 * tid + 1] = ex + g0;
    __syncthreads();
    const int bb = lb[b];
    if (b == 0 && tid == 0) row_ptr[n] = E;

    const int cnt = gcur[b];
    const unsigned* r = rec + (size_t)b * BUCK_CAP;
    for (int i = tid; i < cnt; i += 256) {
        unsigned v = r[i];
        stage[i] = (int)v;  // stash to avoid global re-read
        atomicAdd(&h[v & 255u], 1);
    }
    __syncthreads();
    const int myd = h[tid];
    const int node = b * 256 + tid;
    if (node < n) dis[node] = rsqrtf((float)myd + 1.0f);  // self-loop degree
    int x = myd;
    for (int off = 1; off < 256; off <<= 1) {
        int y = (tid >= off) ? h[tid - off] : 0;
        __syncthreads();
        x += y;
        h[tid] = x;
        __syncthreads();
    }
    const int excl = x - myd;
    if (node < n) row_ptr[node] = bb + excl;
    cur[tid] = bb + excl;
    __syncthreads();
    for (int i = tid; i < cnt; i += 256) {
        unsigned v = (unsigned)stage[i];
        int pos = atomicAdd(&cur[v & 255u], 1);
        ssrc[pos] = (int)(v >> 8);
    }
}

// ---- Phase: MFMA GEMM, grid-strided 64-row tiles --------------------------
template <int K, bool BN, bool XH>
__device__ void ph_gemm(char* sm, const void* __restrict__ Xv,
                        const float* __restrict__ W,
                        const float* __restrict__ dis,
                        const float* __restrict__ stats,
                        const float* __restrict__ g,
                        const float* __restrict__ be,
                        __half* __restrict__ Hp, int n) {
    constexpr int KS = K / 32;
    constexpr int XSTR = K + 8;
    __half* BF = (__half*)sm;                 // KS*4*64*8 halves
    __half* XL = BF + KS * 4 * 64 * 8;        // 64*XSTR halves
    float* muS = (float*)(XL + 64 * XSTR);
    float* wS = muS + 64;
    float* bS = wS + 64;
    const int tid = threadIdx.x;

    if constexpr (BN) {
        if (tid < 64) {
            float s1 = 0.f, s2 = 0.f;
#pragma unroll
            for (int r = 0; r < 8; ++r) {
                s1 += stats[r * 128 + tid];
                s2 += stats[r * 128 + 64 + tid];
            }
            float inv_n = 1.0f / (float)n;
            float m = s1 * inv_n;
            float var = s2 * inv_n - m * m;
            muS[tid] = m;
            wS[tid] = rsqrtf(var + 1e-5f) * g[tid];
            bS[tid] = be[tid];
        }
    }
    for (int i = tid; i < KS * 4 * 64; i += 256) {
        int l = i & 63, fs = i >> 6;
        int ks = fs >> 2, ct = fs & 3;
        int kb = ks * 32 + ((l >> 4) << 3);
        int c = (ct << 4) + (l & 15);
        H8U t;
#pragma unroll
        for (int j = 0; j < 8; ++j) t.h[j] = __float2half_rn(W[(kb + j) * 64 + c]);
        *reinterpret_cast<uint4*>(&BF[i * 8]) = t.u;
    }
    __syncthreads();

    const int wave = tid >> 6, lane = tid & 63;
    const int ntiles = (n + 63) >> 6;
    for (int t = blockIdx.x; t < ntiles; t += gridDim.x) {
        const int row0 = t * 64;
        __syncthreads();  // previous tile's XL readers done
        if constexpr (!XH) {
            constexpr int Q4 = K / 4;
            const float4* X4 = (const float4*)Xv;
            for (int it = 0; it < 64 * Q4 / 256; ++it) {
                int idx = it * 256 + tid;
                int row = idx / Q4, q = idx % Q4;
                int grow = row0 + row;
                float4 v = make_float4(0.f, 0.f, 0.f, 0.f);
                if (grow < n) v = X4[(size_t)grow * Q4 + q];
                *reinterpret_cast<uint2*>(&XL[row * XSTR + q * 4]) =
                    pack4(v.x, v.y, v.z, v.w);
            }
        } else {
            constexpr int QU = K / 4;
            const uint2* Xh = (const uint2*)Xv;
            for (int it = 0; it < 64 * QU / 256; ++it) {
                int idx = it * 256 + tid;
                int row = idx / QU, q = idx % QU;
                int grow = row0 + row;
                float4 v = make_float4(0.f, 0.f, 0.f, 0.f);
                if (grow < n) {
                    v = unpack4(Xh[(size_t)grow * QU + q]);
                    float4 m = *reinterpret_cast<const float4*>(&muS[q * 4]);
                    float4 w4 = *reinterpret_cast<const float4*>(&wS[q * 4]);
                    float4 b4 = *reinterpret_cast<const float4*>(&bS[q * 4]);
                    v.x = fmaxf((v.x - m.x) * w4.x + b4.x, 0.f);
                    v.y = fmaxf((v.y - m.y) * w4.y + b4.y, 0.f);
                    v.z = fmaxf((v.z - m.z) * w4.z + b4.z, 0.f);
                    v.w = fmaxf((v.w - m.w) * w4.w + b4.w, 0.f);
                }
                *reinterpret_cast<uint2*>(&XL[row * XSTR + q * 4]) =
                    pack4(v.x, v.y, v.z, v.w);
            }
        }
        __syncthreads();

        const __half* arow = &XL[(wave * 16 + (lane & 15)) * XSTR + ((lane >> 4) << 3)];
        f16x8 a[KS];
#pragma unroll
        for (int ks = 0; ks < KS; ++ks)
            a[ks] = *reinterpret_cast<const f16x8*>(arow + ks * 32);

        f32x4 acc[4];
#pragma unroll
        for (int ct = 0; ct < 4; ++ct) acc[ct] = (f32x4){0.f, 0.f, 0.f, 0.f};
#pragma unroll
        for (int ct = 0; ct < 4; ++ct)
#pragma unroll
            for (int ks = 0; ks < KS; ++ks) {
                f16x8 b = *reinterpret_cast<const f16x8*>(
                    &BF[((ks * 4 + ct) * 64 + lane) * 8]);
                acc[ct] = __builtin_amdgcn_mfma_f32_16x16x32_f16(a[ks], b, acc[ct], 0, 0, 0);
            }

        const int mbase = row0 + wave * 16 + ((lane >> 4) << 2);
#pragma unroll
        for (int reg = 0; reg < 4; ++reg) {
            int grow = mbase + reg;
            if (grow < n) {
                float dd = dis[grow];
#pragma unroll
                for (int ct = 0; ct < 4; ++ct)
                    Hp[(size_t)grow * 64 + ct * 16 + (lane & 15)] =
                        __float2half_rn(acc[ct][reg] * dd);
            }
        }
    }
}

// ---- Phase: gather + fused BN stats ---------------------------------------
__device__ void ph_gather(char* sm, const int* __restrict__ row_ptr,
                          const int* __restrict__ ssrc,
                          const float* __restrict__ dis,
                          const uint4* __restrict__ Hp, uint4* __restrict__ AGG,
                          float* __restrict__ stats, int n) {
    float* red1 = (float*)sm;     // [32][64]
    float* red2 = red1 + 2048;    // [32][64]
    const int tid = threadIdx.x;
    const int g = tid >> 3, fi = tid & 7;
    float sacc[8] = {}, qacc[8] = {};
    for (int d = blockIdx.x * 32 + g; d < n; d += gridDim.x * 32) {
        int r0 = row_ptr[d], r1 = row_ptr[d + 1];
        float a[8] = {};
        upadd8(Hp[(size_t)d * 8 + fi], a);  // self-loop contribution
        int p = r0;
        for (; p + 7 < r1; p += 8) {
            int s0 = ssrc[p], s1 = ssrc[p + 1], s2 = ssrc[p + 2], s3 = ssrc[p + 3];
            int s4 = ssrc[p + 4], s5 = ssrc[p + 5], s6 = ssrc[p + 6], s7 = ssrc[p + 7];
            uint4 q0 = Hp[(size_t)s0 * 8 + fi];
            uint4 q1 = Hp[(size_t)s1 * 8 + fi];
            uint4 q2 = Hp[(size_t)s2 * 8 + fi];
            uint4 q3 = Hp[(size_t)s3 * 8 + fi];
            uint4 q4 = Hp[(size_t)s4 * 8 + fi];
            uint4 q5 = Hp[(size_t)s5 * 8 + fi];
            uint4 q6 = Hp[(size_t)s6 * 8 + fi];
            uint4 q7 = Hp[(size_t)s7 * 8 + fi];
            upadd8(q0, a); upadd8(q1, a); upadd8(q2, a); upadd8(q3, a);
            upadd8(q4, a); upadd8(q5, a); upadd8(q6, a); upadd8(q7, a);
        }
        for (; p + 3 < r1; p += 4) {
            int s0 = ssrc[p], s1 = ssrc[p + 1], s2 = ssrc[p + 2], s3 = ssrc[p + 3];
            uint4 q0 = Hp[(size_t)s0 * 8 + fi];
            uint4 q1 = Hp[(size_t)s1 * 8 + fi];
            uint4 q2 = Hp[(size_t)s2 * 8 + fi];
            uint4 q3 = Hp[(size_t)s3 * 8 + fi];
            upadd8(q0, a); upadd8(q1, a); upadd8(q2, a); upadd8(q3, a);
        }
        for (; p < r1; ++p) upadd8(Hp[(size_t)ssrc[p] * 8 + fi], a);
        float dd = dis[d];
        H8U o;
#pragma unroll
        for (int i = 0; i < 8; ++i) {
            float v = a[i] * dd;
            o.h[i] = __float2half_rn(v);
            sacc[i] += v;
            qacc[i] += v * v;
        }
        AGG[(size_t)d * 8 + fi] = o.u;
    }
#pragma unroll
    for (int j = 0; j < 8; ++j) {
        red1[g * 64 + fi * 8 + j] = sacc[j];
        red2[g * 64 + fi * 8 + j] = qacc[j];
    }
    __syncthreads();
    if (tid < 64) {
        float s = 0.f;
#pragma unroll
        for (int r = 0; r < 32; ++r) s += red1[r * 64 + tid];
        atomicAdd(&stats[(blockIdx.x & 7) * 128 + tid], s);
    } else if (tid < 128) {
        int f = tid - 64;
        float s = 0.f;
#pragma unroll
        for (int r = 0; r < 32; ++r) s += red2[r * 64 + f];
        atomicAdd(&stats[(blockIdx.x & 7) * 128 + 64 + f], s);
    }
    __syncthreads();  // red reuse safety for next phase using pool
}

// ---- Phase: head ----------------------------------------------------------
__device__ void ph_head(char* sm, const uint2* __restrict__ X,
                        const float* __restrict__ stats,
                        const float* __restrict__ g, const float* __restrict__ be,
                        const float* __restrict__ w1, const float* __restrict__ b1,
                        const float* __restrict__ w2, const float* __restrict__ b2,
                        float* __restrict__ out, int n) {
    float* w1s = (float*)sm;        // 2048
    float* muS = w1s + 2048;        // 64
    float* wS = muS + 64;
    float* bS = wS + 64;
    float* b1s = bS + 64;           // 32
    float* w2s = b1s + 32;          // 64
    float* b2s = w2s + 64;          // 2
    int tid = threadIdx.x;
    for (int i = tid; i < 512; i += 256)
        reinterpret_cast<float4*>(w1s)[i] = reinterpret_cast<const float4*>(w1)[i];
    if (tid < 32) b1s[tid] = b1[tid];
    if (tid >= 64 && tid < 128) w2s[tid - 64] = w2[tid - 64];
    if (tid >= 128 && tid < 130) b2s[tid - 128] = b2[tid - 128];
    if (tid < 64) {
        float s1 = 0.f, s2 = 0.f;
#pragma unroll
        for (int r = 0; r < 8; ++r) {
            s1 += stats[r * 128 + tid];
            s2 += stats[r * 128 + 64 + tid];
        }
        float inv_n = 1.0f / (float)n;
        float m = s1 * inv_n;
        float var = s2 * inv_n - m * m;
        muS[tid] = m;
        wS[tid] = rsqrtf(var + 1e-5f) * g[tid];
        bS[tid] = be[tid];
    }
    __syncthreads();
    for (int row = blockIdx.x * NTHR + tid; row < n; row += gridDim.x * NTHR) {
        float4 h[8];
#pragma unroll
        for (int j4 = 0; j4 < 8; ++j4) h[j4] = reinterpret_cast<float4*>(b1s)[j4];
#pragma unroll
        for (int k4 = 0; k4 < 16; ++k4) {
            float4 xv = unpack4(X[(size_t)row * 16 + k4]);
#pragma unroll
            for (int kk = 0; kk < 4; ++kk) {
                int k = k4 * 4 + kk;
                float raw = (kk == 0) ? xv.x : (kk == 1) ? xv.y : (kk == 2) ? xv.z : xv.w;
                float xk = fmaxf((raw - muS[k]) * wS[k] + bS[k], 0.f);
                const float4* wrow = reinterpret_cast<const float4*>(&w1s[k * 32]);
#pragma unroll
                for (int j4 = 0; j4 < 8; ++j4) {
                    float4 wv = wrow[j4];
                    h[j4].x += xk * wv.x; h[j4].y += xk * wv.y;
                    h[j4].z += xk * wv.z; h[j4].w += xk * wv.w;
                }
            }
        }
        float o0 = b2s[0], o1 = b2s[1];
#pragma unroll
        for (int j4 = 0; j4 < 8; ++j4) {
            float hv[4] = {h[j4].x, h[j4].y, h[j4].z, h[j4].w};
#pragma unroll
            for (int c = 0; c < 4; ++c) {
                float hj = fmaxf(hv[c], 0.f);
                int j = j4 * 4 + c;
                o0 += hj * w2s[2 * j];
                o1 += hj * w2s[2 * j + 1];
            }
        }
        float m = fmaxf(o0, o1);
        float l = __logf(__expf(o0 - m) + __expf(o1 - m));
        reinterpret_cast<float2*>(out)[row] = make_float2(o0 - m - l, o1 - m - l);
    }
}

// ---- The mega-kernel ------------------------------------------------------
__global__ __launch_bounds__(NTHR, 4) void k_mega(
    const float* __restrict__ x, const int* __restrict__ src,
    const int* __restrict__ dst,
    const float* W0, const float* W1, const float* W2,
    const float* g0, const float* be0, const float* g1, const float* be1,
    const float* g2, const float* be2,
    const float* fc1w, const float* fc1b, const float* fc2w, const float* fc2b,
    float* out,
    int* ctrl, int* gcur, float* stats, float* dis, int* row_ptr,
    unsigned* rec, int* ssrc, __half* B0, __half* B1,
    int n, int E, int NB) {
    __shared__ __align__(16) char sm[34816];
    int* A = ctrl;            // gate flag
    int* cnt = ctrl + 16;     // barrier slots [0..15]

    // P0: block0 init (counters, gcur, stats) then release gate.
    if (blockIdx.x == 0) {
        int t = threadIdx.x;
        if (t < 16) cnt[t] = 0;
        gcur[t] = 0; gcur[t + 256] = 0;
#pragma unroll
        for (int k = 0; k < 12; ++k) stats[k * 256 + t] = 0.f;
        __syncthreads();
        if (t == 0) {
            __threadfence();
            __hip_atomic_store(A, MAGIC, __ATOMIC_RELEASE, __HIP_MEMORY_SCOPE_AGENT);
        }
    }
    if (threadIdx.x == 0) {
        while (__hip_atomic_fetch_add(A, 0, __ATOMIC_ACQ_REL,
                                      __HIP_MEMORY_SCOPE_AGENT) != MAGIC)
            __builtin_amdgcn_s_sleep(16);
        __threadfence();
    }
    __syncthreads();

    ph_part(sm, src, dst, gcur, rec, E, NB);
    gbar(cnt, 0);
    ph_bscat(sm, gcur, rec, dis, row_ptr, ssrc, n, NB, E);
    gbar(cnt, 1);
    ph_gemm<128, false, false>(sm, x, W0, dis, nullptr, nullptr, nullptr, B0, n);
    gbar(cnt, 2);
    ph_gather(sm, row_ptr, ssrc, dis, (const uint4*)B0, (uint4*)B1, stats + 0, n);
    gbar(cnt, 3);
    ph_gemm<64, true, true>(sm, B1, W1, dis, stats + 0, g0, be0, B0, n);
    gbar(cnt, 4);
    ph_gather(sm, row_ptr, ssrc, dis, (const uint4*)B0, (uint4*)B1, stats + 1024, n);
    gbar(cnt, 5);
    ph_gemm<64, true, true>(sm, B1, W2, dis, stats + 1024, g1, be1, B0, n);
    gbar(cnt, 6);
    ph_gather(sm, row_ptr, ssrc, dis, (const uint4*)B0, (uint4*)B1, stats + 2048, n);
    gbar(cnt, 7);
    ph_head(sm, (const uint2*)B1, stats + 2048, g2, be2, fc1w, fc1b, fc2w, fc2b,
            out, n);
    gbar(cnt, 8);
    if (blockIdx.x == 0 && threadIdx.x == 0)
        __hip_atomic_store(A, 0, __ATOMIC_RELEASE, __HIP_MEMORY_SCOPE_AGENT);
}

extern "C" void kernel_launch(void* const* d_in, const int* in_sizes, int n_in,
                              void* d_out, int out_size, void* d_ws, size_t ws_size,
                              hipStream_t stream) {
    const float* x    = (const float*)d_in[0];
    const int*   ei   = (const int*)d_in[1];
    const float* W0   = (const float*)d_in[2];
    const float* W1   = (const float*)d_in[4];
    const float* W2   = (const float*)d_in[6];
    const float* g0   = (const float*)d_in[8];
    const float* be0  = (const float*)d_in[9];
    const float* g1   = (const float*)d_in[10];
    const float* be1  = (const float*)d_in[11];
    const float* g2   = (const float*)d_in[12];
    const float* be2  = (const float*)d_in[13];
    const float* fc1w = (const float*)d_in[14];
    const float* fc1b = (const float*)d_in[15];
    const float* fc2w = (const float*)d_in[16];
    const float* fc2b = (const float*)d_in[17];

    const int N = in_sizes[0] / 128;
    const int E = in_sizes[1] / 2;
    const int* srcp = ei;
    const int* dstp = ei + E;
    const int NB = (N + 255) >> 8;  // 256-node buckets (<=512)

    char* ws = (char*)d_ws;
    size_t off = 0;
    auto alloc = [&](size_t bytes) -> void* {
        void* p = ws + off;
        off = (off + bytes + 255) & ~(size_t)255;
        return p;
    };
    int*      ctrl    = (int*)alloc(64 * 4);
    int*      gcur    = (int*)alloc(512 * 4);
    float*    stats   = (float*)alloc(3 * 8 * 128 * 4);
    float*    dis     = (float*)alloc((size_t)N * 4);
    int*      row_ptr = (int*)alloc((size_t)(N + 1) * 4);
    unsigned* rec     = (unsigned*)alloc((size_t)NB * BUCK_CAP * 4);
    int*      ssrc    = (int*)alloc((size_t)E * 4);
    __half*   B0      = (__half*)alloc((size_t)N * 64 * 2);
    __half*   B1      = (__half*)alloc((size_t)N * 64 * 2);

    k_mega<<<NBLK, NTHR, 0, stream>>>(
        x, srcp, dstp, W0, W1, W2, g0, be0, g1, be1, g2, be2,
        fc1w, fc1b, fc2w, fc2b, (float*)d_out,
        ctrl, gcur, stats, dis, row_ptr, rec, ssrc, B0, B1, N, E, NB);
}

// Round 10
// 2195.417 us; speedup vs baseline: 2.2355x; 2.2355x over previous
//
#include <hip/hip_runtime.h>
#include <hip/hip_fp16.h>
#include <math.h>

// ---------------------------------------------------------------------------
// GCN: 3x (GCNConv -> BatchNorm -> ReLU) -> fc1+ReLU -> fc2 -> log_softmax
// N=100000, E=1600000, IN=128, HID=64, classes=2.
// SINGLE persistent mega-kernel: CSR build + 3x(MFMA gemm -> gather+stats) +
// head, separated by device-wide barriers.
// R10 fix vs R9: barrier POLL is a plain atomic LOAD (acquire), not a
// fetch_add RMW — R9's RMW-spin from 1024 blocks serialized the L2 atomic
// unit (~500us/barrier, 23x regression). Arrivals still use fetch_add.
// Co-residency: 1024 blocks x 256 thr, __launch_bounds__(256,4) (VGPR<=128,
// 16 waves/CU), LDS 34.8KB -> 4 blocks/CU exact.
// Poison-proof init: MAGIC gate; gate reset by block0 after head (all blocks
// passed the gate once barrier 0 completed, so reset needs no extra barrier).
// ---------------------------------------------------------------------------

#define NBLK 1024
#define NTHR 256
#define BUCK_CAP 6144
#define PART_CHUNK 4096
#define MAGIC 0x7E57C0DE

typedef _Float16 f16x8 __attribute__((ext_vector_type(8)));
typedef float f32x4 __attribute__((ext_vector_type(4)));

union H4U { uint2 u; __half h[4]; };
union H8U { uint4 u; __half h[8]; };

__device__ inline uint2 pack4(float a, float b, float c, float d) {
    H4U t;
    t.h[0] = __float2half_rn(a); t.h[1] = __float2half_rn(b);
    t.h[2] = __float2half_rn(c); t.h[3] = __float2half_rn(d);
    return t.u;
}
__device__ inline float4 unpack4(uint2 u) {
    H4U t; t.u = u;
    return make_float4(__half2float(t.h[0]), __half2float(t.h[1]),
                       __half2float(t.h[2]), __half2float(t.h[3]));
}
__device__ inline void upadd8(uint4 u, float* a) {
    H8U t; t.u = u;
#pragma unroll
    for (int i = 0; i < 8; ++i) a[i] += __half2float(t.h[i]);
}

// Device-wide barrier. Arrival = atomic add (RMW); poll = atomic LOAD only.
__device__ __forceinline__ void gbar(int* cnt, int idx) {
    __syncthreads();
    if (threadIdx.x == 0) {
        __threadfence();  // release: drain this block's writes
        __hip_atomic_fetch_add(&cnt[idx], 1, __ATOMIC_RELEASE,
                               __HIP_MEMORY_SCOPE_AGENT);
        while (__hip_atomic_load(&cnt[idx], __ATOMIC_ACQUIRE,
                                 __HIP_MEMORY_SCOPE_AGENT) < NBLK)
            __builtin_amdgcn_s_sleep(2);
        __threadfence();  // acquire: invalidate stale cached lines
    }
    __syncthreads();
}

// ---- Phase: bucket partition (bucket = dst>>8), 4096-edge chunks ----------
__device__ void ph_part(char* sm, const int* __restrict__ src,
                        const int* __restrict__ dst, int* __restrict__ gcur,
                        unsigned* __restrict__ rec, int E, int NB) {
    int* hist = (int*)sm;        // 512 ints
    int* gbase = hist + 512;     // 512 ints
    const int tid = threadIdx.x;
    for (int chunk = blockIdx.x; chunk * PART_CHUNK < E; chunk += gridDim.x) {
        const int e0 = chunk * PART_CHUNK;
        const int e1 = min(e0 + PART_CHUNK, E);
        hist[tid] = 0; hist[tid + 256] = 0;
        __syncthreads();
        for (int i = e0 + tid; i < e1; i += 256)
            atomicAdd(&hist[dst[i] >> 8], 1);
        __syncthreads();
        for (int b = tid; b < NB; b += 256) {
            int c = hist[b];
            gbase[b] = c ? atomicAdd(&gcur[b], c) : 0;
            hist[b] = 0;  // reuse as cursor
        }
        __syncthreads();
        for (int i = e0 + tid; i < e1; i += 256) {
            int d = dst[i], s = src[i];
            int b = d >> 8;
            int off = atomicAdd(&hist[b], 1);
            rec[(size_t)b * BUCK_CAP + gbase[b] + off] =
                ((unsigned)s << 8) | (unsigned)(d & 255);
        }
        __syncthreads();
    }
}

// ---- Phase: per-bucket hist+scan+scatter -> dis, row_ptr, ssrc ------------
__device__ void ph_bscat(char* sm, const int* __restrict__ gcur,
                         const unsigned* __restrict__ rec,
                         float* __restrict__ dis, int* __restrict__ row_ptr,
                         int* __restrict__ ssrc, int n, int NB, int E) {
    if ((int)blockIdx.x >= NB) return;  // no barriers inside: safe
    int* h     = (int*)sm;        // 256
    int* cur   = h + 256;         // 256
    int* lb    = cur + 256;       // 512
    int* stmp  = lb + 512;        // 256
    int* stage = stmp + 256;      // 6144 (24 KB)
    const int b = blockIdx.x, tid = threadIdx.x;
    int g0 = (2 * tid < NB) ? gcur[2 * tid] : 0;
    int g1 = (2 * tid + 1 < NB) ? gcur[2 * tid + 1] : 0;
    int ps = g0 + g1;
    stmp[tid] = ps;
    h[tid] = 0;
    __syncthreads();
    int xx = ps;
    for (int off = 1; off < 256; off <<= 1) {
        int y = (tid >= off) ? stmp[tid - off] : 0;
        __syncthreads();
        xx += y;
        stmp[tid] = xx;
        __syncthreads();
    }
    int ex = xx - ps;
    lb[2 * tid] = ex;
    lb[2 * tid + 1] = ex + g0;
    __syncthreads();
    const int bb = lb[b];
    if (b == 0 && tid == 0) row_ptr[n] = E;

    const int cnt = gcur[b];
    const unsigned* r = rec + (size_t)b * BUCK_CAP;
    for (int i = tid; i < cnt; i += 256) {
        unsigned v = r[i];
        stage[i] = (int)v;  // stash to avoid global re-read
        atomicAdd(&h[v & 255u], 1);
    }
    __syncthreads();
    const int myd = h[tid];
    const int node = b * 256 + tid;
    if (node < n) dis[node] = rsqrtf((float)myd + 1.0f);  // self-loop degree
    int x = myd;
    for (int off = 1; off < 256; off <<= 1) {
        int y = (tid >= off) ? h[tid - off] : 0;
        __syncthreads();
        x += y;
        h[tid] = x;
        __syncthreads();
    }
    const int excl = x - myd;
    if (node < n) row_ptr[node] = bb + excl;
    cur[tid] = bb + excl;
    __syncthreads();
    for (int i = tid; i < cnt; i += 256) {
        unsigned v = (unsigned)stage[i];
        int pos = atomicAdd(&cur[v & 255u], 1);
        ssrc[pos] = (int)(v >> 8);
    }
}

// ---- Phase: MFMA GEMM, grid-strided 64-row tiles --------------------------
template <int K, bool BN, bool XH>
__device__ void ph_gemm(char* sm, const void* __restrict__ Xv,
                        const float* __restrict__ W,
                        const float* __restrict__ dis,
                        const float* __restrict__ stats,
                        const float* __restrict__ g,
                        const float* __restrict__ be,
                        __half* __restrict__ Hp, int n) {
    constexpr int KS = K / 32;
    constexpr int XSTR = K + 8;
    __half* BF = (__half*)sm;                 // KS*4*64*8 halves
    __half* XL = BF + KS * 4 * 64 * 8;        // 64*XSTR halves
    float* muS = (float*)(XL + 64 * XSTR);
    float* wS = muS + 64;
    float* bS = wS + 64;
    const int tid = threadIdx.x;

    if constexpr (BN) {
        if (tid < 64) {
            float s1 = 0.f, s2 = 0.f;
#pragma unroll
            for (int r = 0; r < 8; ++r) {
                s1 += stats[r * 128 + tid];
                s2 += stats[r * 128 + 64 + tid];
            }
            float inv_n = 1.0f / (float)n;
            float m = s1 * inv_n;
            float var = s2 * inv_n - m * m;
            muS[tid] = m;
            wS[tid] = rsqrtf(var + 1e-5f) * g[tid];
            bS[tid] = be[tid];
        }
    }
    for (int i = tid; i < KS * 4 * 64; i += 256) {
        int l = i & 63, fs = i >> 6;
        int ks = fs >> 2, ct = fs & 3;
        int kb = ks * 32 + ((l >> 4) << 3);
        int c = (ct << 4) + (l & 15);
        H8U t;
#pragma unroll
        for (int j = 0; j < 8; ++j) t.h[j] = __float2half_rn(W[(kb + j) * 64 + c]);
        *reinterpret_cast<uint4*>(&BF[i * 8]) = t.u;
    }
    __syncthreads();

    const int wave = tid >> 6, lane = tid & 63;
    const int ntiles = (n + 63) >> 6;
    for (int t = blockIdx.x; t < ntiles; t += gridDim.x) {
        const int row0 = t * 64;
        __syncthreads();  // previous tile's XL readers done
        if constexpr (!XH) {
            constexpr int Q4 = K / 4;
            const float4* X4 = (const float4*)Xv;
            for (int it = 0; it < 64 * Q4 / 256; ++it) {
                int idx = it * 256 + tid;
                int row = idx / Q4, q = idx % Q4;
                int grow = row0 + row;
                float4 v = make_float4(0.f, 0.f, 0.f, 0.f);
                if (grow < n) v = X4[(size_t)grow * Q4 + q];
                *reinterpret_cast<uint2*>(&XL[row * XSTR + q * 4]) =
                    pack4(v.x, v.y, v.z, v.w);
            }
        } else {
            constexpr int QU = K / 4;
            const uint2* Xh = (const uint2*)Xv;
            for (int it = 0; it < 64 * QU / 256; ++it) {
                int idx = it * 256 + tid;
                int row = idx / QU, q = idx % QU;
                int grow = row0 + row;
                float4 v = make_float4(0.f, 0.f, 0.f, 0.f);
                if (grow < n) {
                    v = unpack4(Xh[(size_t)grow * QU + q]);
                    float4 m = *reinterpret_cast<const float4*>(&muS[q * 4]);
                    float4 w4 = *reinterpret_cast<const float4*>(&wS[q * 4]);
                    float4 b4 = *reinterpret_cast<const float4*>(&bS[q * 4]);
                    v.x = fmaxf((v.x - m.x) * w4.x + b4.x, 0.f);
                    v.y = fmaxf((v.y - m.y) * w4.y + b4.y, 0.f);
                    v.z = fmaxf((v.z - m.z) * w4.z + b4.z, 0.f);
                    v.w = fmaxf((v.w - m.w) * w4.w + b4.w, 0.f);
                }
                *reinterpret_cast<uint2*>(&XL[row * XSTR + q * 4]) =
                    pack4(v.x, v.y, v.z, v.w);
            }
        }
        __syncthreads();

        const __half* arow = &XL[(wave * 16 + (lane & 15)) * XSTR + ((lane >> 4) << 3)];
        f16x8 a[KS];
#pragma unroll
        for (int ks = 0; ks < KS; ++ks)
            a[ks] = *reinterpret_cast<const f16x8*>(arow + ks * 32);

        f32x4 acc[4];
#pragma unroll
        for (int ct = 0; ct < 4; ++ct) acc[ct] = (f32x4){0.f, 0.f, 0.f, 0.f};
#pragma unroll
        for (int ct = 0; ct < 4; ++ct)
#pragma unroll
            for (int ks = 0; ks < KS; ++ks) {
                f16x8 b = *reinterpret_cast<const f16x8*>(
                    &BF[((ks * 4 + ct) * 64 + lane) * 8]);
                acc[ct] = __builtin_amdgcn_mfma_f32_16x16x32_f16(a[ks], b, acc[ct], 0, 0, 0);
            }

        const int mbase = row0 + wave * 16 + ((lane >> 4) << 2);
#pragma unroll
        for (int reg = 0; reg < 4; ++reg) {
            int grow = mbase + reg;
            if (grow < n) {
                float dd = dis[grow];
#pragma unroll
                for (int ct = 0; ct < 4; ++ct)
                    Hp[(size_t)grow * 64 + ct * 16 + (lane & 15)] =
                        __float2half_rn(acc[ct][reg] * dd);
            }
        }
    }
}

// ---- Phase: gather + fused BN stats ---------------------------------------
__device__ void ph_gather(char* sm, const int* __restrict__ row_ptr,
                          const int* __restrict__ ssrc,
                          const float* __restrict__ dis,
                          const uint4* __restrict__ Hp, uint4* __restrict__ AGG,
                          float* __restrict__ stats, int n) {
    float* red1 = (float*)sm;     // [32][64]
    float* red2 = red1 + 2048;    // [32][64]
    const int tid = threadIdx.x;
    const int g = tid >> 3, fi = tid & 7;
    float sacc[8] = {}, qacc[8] = {};
    for (int d = blockIdx.x * 32 + g; d < n; d += gridDim.x * 32) {
        int r0 = row_ptr[d], r1 = row_ptr[d + 1];
        float a[8] = {};
        upadd8(Hp[(size_t)d * 8 + fi], a);  // self-loop contribution
        int p = r0;
        for (; p + 7 < r1; p += 8) {
            int s0 = ssrc[p], s1 = ssrc[p + 1], s2 = ssrc[p + 2], s3 = ssrc[p + 3];
            int s4 = ssrc[p + 4], s5 = ssrc[p + 5], s6 = ssrc[p + 6], s7 = ssrc[p + 7];
            uint4 q0 = Hp[(size_t)s0 * 8 + fi];
            uint4 q1 = Hp[(size_t)s1 * 8 + fi];
            uint4 q2 = Hp[(size_t)s2 * 8 + fi];
            uint4 q3 = Hp[(size_t)s3 * 8 + fi];
            uint4 q4 = Hp[(size_t)s4 * 8 + fi];
            uint4 q5 = Hp[(size_t)s5 * 8 + fi];
            uint4 q6 = Hp[(size_t)s6 * 8 + fi];
            uint4 q7 = Hp[(size_t)s7 * 8 + fi];
            upadd8(q0, a); upadd8(q1, a); upadd8(q2, a); upadd8(q3, a);
            upadd8(q4, a); upadd8(q5, a); upadd8(q6, a); upadd8(q7, a);
        }
        for (; p + 3 < r1; p += 4) {
            int s0 = ssrc[p], s1 = ssrc[p + 1], s2 = ssrc[p + 2], s3 = ssrc[p + 3];
            uint4 q0 = Hp[(size_t)s0 * 8 + fi];
            uint4 q1 = Hp[(size_t)s1 * 8 + fi];
            uint4 q2 = Hp[(size_t)s2 * 8 + fi];
            uint4 q3 = Hp[(size_t)s3 * 8 + fi];
            upadd8(q0, a); upadd8(q1, a); upadd8(q2, a); upadd8(q3, a);
        }
        for (; p < r1; ++p) upadd8(Hp[(size_t)ssrc[p] * 8 + fi], a);
        float dd = dis[d];
        H8U o;
#pragma unroll
        for (int i = 0; i < 8; ++i) {
            float v = a[i] * dd;
            o.h[i] = __float2half_rn(v);
            sacc[i] += v;
            qacc[i] += v * v;
        }
        AGG[(size_t)d * 8 + fi] = o.u;
    }
#pragma unroll
    for (int j = 0; j < 8; ++j) {
        red1[g * 64 + fi * 8 + j] = sacc[j];
        red2[g * 64 + fi * 8 + j] = qacc[j];
    }
    __syncthreads();
    if (tid < 64) {
        float s = 0.f;
#pragma unroll
        for (int r = 0; r < 32; ++r) s += red1[r * 64 + tid];
        atomicAdd(&stats[(blockIdx.x & 7) * 128 + tid], s);
    } else if (tid < 128) {
        int f = tid - 64;
        float s = 0.f;
#pragma unroll
        for (int r = 0; r < 32; ++r) s += red2[r * 64 + f];
        atomicAdd(&stats[(blockIdx.x & 7) * 128 + 64 + f], s);
    }
    __syncthreads();  // red reuse safety for next phase using pool
}

// ---- Phase: head ----------------------------------------------------------
__device__ void ph_head(char* sm, const uint2* __restrict__ X,
                        const float* __restrict__ stats,
                        const float* __restrict__ g, const float* __restrict__ be,
                        const float* __restrict__ w1, const float* __restrict__ b1,
                        const float* __restrict__ w2, const float* __restrict__ b2,
                        float* __restrict__ out, int n) {
    float* w1s = (float*)sm;        // 2048
    float* muS = w1s + 2048;        // 64
    float* wS = muS + 64;
    float* bS = wS + 64;
    float* b1s = bS + 64;           // 32
    float* w2s = b1s + 32;          // 64
    float* b2s = w2s + 64;          // 2
    int tid = threadIdx.x;
    for (int i = tid; i < 512; i += 256)
        reinterpret_cast<float4*>(w1s)[i] = reinterpret_cast<const float4*>(w1)[i];
    if (tid < 32) b1s[tid] = b1[tid];
    if (tid >= 64 && tid < 128) w2s[tid - 64] = w2[tid - 64];
    if (tid >= 128 && tid < 130) b2s[tid - 128] = b2[tid - 128];
    if (tid < 64) {
        float s1 = 0.f, s2 = 0.f;
#pragma unroll
        for (int r = 0; r < 8; ++r) {
            s1 += stats[r * 128 + tid];
            s2 += stats[r * 128 + 64 + tid];
        }
        float inv_n = 1.0f / (float)n;
        float m = s1 * inv_n;
        float var = s2 * inv_n - m * m;
        muS[tid] = m;
        wS[tid] = rsqrtf(var + 1e-5f) * g[tid];
        bS[tid] = be[tid];
    }
    __syncthreads();
    for (int row = blockIdx.x * NTHR + tid; row < n; row += gridDim.x * NTHR) {
        float4 h[8];
#pragma unroll
        for (int j4 = 0; j4 < 8; ++j4) h[j4] = reinterpret_cast<float4*>(b1s)[j4];
#pragma unroll
        for (int k4 = 0; k4 < 16; ++k4) {
            float4 xv = unpack4(X[(size_t)row * 16 + k4]);
#pragma unroll
            for (int kk = 0; kk < 4; ++kk) {
                int k = k4 * 4 + kk;
                float raw = (kk == 0) ? xv.x : (kk == 1) ? xv.y : (kk == 2) ? xv.z : xv.w;
                float xk = fmaxf((raw - muS[k]) * wS[k] + bS[k], 0.f);
                const float4* wrow = reinterpret_cast<const float4*>(&w1s[k * 32]);
#pragma unroll
                for (int j4 = 0; j4 < 8; ++j4) {
                    float4 wv = wrow[j4];
                    h[j4].x += xk * wv.x; h[j4].y += xk * wv.y;
                    h[j4].z += xk * wv.z; h[j4].w += xk * wv.w;
                }
            }
        }
        float o0 = b2s[0], o1 = b2s[1];
#pragma unroll
        for (int j4 = 0; j4 < 8; ++j4) {
            float hv[4] = {h[j4].x, h[j4].y, h[j4].z, h[j4].w};
#pragma unroll
            for (int c = 0; c < 4; ++c) {
                float hj = fmaxf(hv[c], 0.f);
                int j = j4 * 4 + c;
                o0 += hj * w2s[2 * j];
                o1 += hj * w2s[2 * j + 1];
            }
        }
        float m = fmaxf(o0, o1);
        float l = __logf(__expf(o0 - m) + __expf(o1 - m));
        reinterpret_cast<float2*>(out)[row] = make_float2(o0 - m - l, o1 - m - l);
    }
}

// ---- The mega-kernel ------------------------------------------------------
__global__ __launch_bounds__(NTHR, 4) void k_mega(
    const float* __restrict__ x, const int* __restrict__ src,
    const int* __restrict__ dst,
    const float* W0, const float* W1, const float* W2,
    const float* g0, const float* be0, const float* g1, const float* be1,
    const float* g2, const float* be2,
    const float* fc1w, const float* fc1b, const float* fc2w, const float* fc2b,
    float* out,
    int* ctrl, int* gcur, float* stats, float* dis, int* row_ptr,
    unsigned* rec, int* ssrc, __half* B0, __half* B1,
    int n, int E, int NB) {
    __shared__ __align__(16) char sm[34816];
    int* A = ctrl;            // gate flag
    int* cnt = ctrl + 16;     // barrier slots [0..15]

    // P0: block0 init (counters, gcur, stats) then release gate.
    if (blockIdx.x == 0) {
        int t = threadIdx.x;
        if (t < 16) cnt[t] = 0;
        gcur[t] = 0; gcur[t + 256] = 0;
#pragma unroll
        for (int k = 0; k < 12; ++k) stats[k * 256 + t] = 0.f;
        __syncthreads();
        if (t == 0) {
            __threadfence();
            __hip_atomic_store(A, MAGIC, __ATOMIC_RELEASE, __HIP_MEMORY_SCOPE_AGENT);
        }
    }
    if (threadIdx.x == 0) {
        while (__hip_atomic_load(A, __ATOMIC_ACQUIRE,
                                 __HIP_MEMORY_SCOPE_AGENT) != MAGIC)
            __builtin_amdgcn_s_sleep(2);
        __threadfence();
    }
    __syncthreads();

    ph_part(sm, src, dst, gcur, rec, E, NB);
    gbar(cnt, 0);
    ph_bscat(sm, gcur, rec, dis, row_ptr, ssrc, n, NB, E);
    gbar(cnt, 1);
    ph_gemm<128, false, false>(sm, x, W0, dis, nullptr, nullptr, nullptr, B0, n);
    gbar(cnt, 2);
    ph_gather(sm, row_ptr, ssrc, dis, (const uint4*)B0, (uint4*)B1, stats + 0, n);
    gbar(cnt, 3);
    ph_gemm<64, true, true>(sm, B1, W1, dis, stats + 0, g0, be0, B0, n);
    gbar(cnt, 4);
    ph_gather(sm, row_ptr, ssrc, dis, (const uint4*)B0, (uint4*)B1, stats + 1024, n);
    gbar(cnt, 5);
    ph_gemm<64, true, true>(sm, B1, W2, dis, stats + 1024, g1, be1, B0, n);
    gbar(cnt, 6);
    ph_gather(sm, row_ptr, ssrc, dis, (const uint4*)B0, (uint4*)B1, stats + 2048, n);
    gbar(cnt, 7);
    ph_head(sm, (const uint2*)B1, stats + 2048, g2, be2, fc1w, fc1b, fc2w, fc2b,
            out, n);
    // All blocks passed the gate (guaranteed since barrier 0 completed), so
    // block 0 can reset it without a final barrier.
    if (blockIdx.x == 0 && threadIdx.x == 0)
        __hip_atomic_store(A, 0, __ATOMIC_RELEASE, __HIP_MEMORY_SCOPE_AGENT);
}

extern "C" void kernel_launch(void* const* d_in, const int* in_sizes, int n_in,
                              void* d_out, int out_size, void* d_ws, size_t ws_size,
                              hipStream_t stream) {
    const float* x    = (const float*)d_in[0];
    const int*   ei   = (const int*)d_in[1];
    const float* W0   = (const float*)d_in[2];
    const float* W1   = (const float*)d_in[4];
    const float* W2   = (const float*)d_in[6];
    const float* g0   = (const float*)d_in[8];
    const float* be0  = (const float*)d_in[9];
    const float* g1   = (const float*)d_in[10];
    const float* be1  = (const float*)d_in[11];
    const float* g2   = (const float*)d_in[12];
    const float* be2  = (const float*)d_in[13];
    const float* fc1w = (const float*)d_in[14];
    const float* fc1b = (const float*)d_in[15];
    const float* fc2w = (const float*)d_in[16];
    const float* fc2b = (const float*)d_in[17];

    const int N = in_sizes[0] / 128;
    const int E = in_sizes[1] / 2;
    const int* srcp = ei;
    const int* dstp = ei + E;
    const int NB = (N + 255) >> 8;  // 256-node buckets (<=512)

    char* ws = (char*)d_ws;
    size_t off = 0;
    auto alloc = [&](size_t bytes) -> void* {
        void* p = ws + off;
        off = (off + bytes + 255) & ~(size_t)255;
        return p;
    };
    int*      ctrl    = (int*)alloc(64 * 4);
    int*      gcur    = (int*)alloc(512 * 4);
    float*    stats   = (float*)alloc(3 * 8 * 128 * 4);
    float*    dis     = (float*)alloc((size_t)N * 4);
    int*      row_ptr = (int*)alloc((size_t)(N + 1) * 4);
    unsigned* rec     = (unsigned*)alloc((size_t)NB * BUCK_CAP * 4);
    int*      ssrc    = (int*)alloc((size_t)E * 4);
    __half*   B0      = (__half*)alloc((size_t)N * 64 * 2);
    __half*   B1      = (__half*)alloc((size_t)N * 64 * 2);

    k_mega<<<NBLK, NTHR, 0, stream>>>(
        x, srcp, dstp, W0, W1, W2, g0, be0, g1, be1, g2, be2,
        fc1w, fc1b, fc2w, fc2b, (float*)d_out,
        ctrl, gcur, stats, dis, row_ptr, rec, ssrc, B0, B1, N, E, NB);
}

// Round 11
// 859.487 us; speedup vs baseline: 5.7103x; 2.5543x over previous
//
#include <hip/hip_runtime.h>
#include <hip/hip_fp16.h>
#include <math.h>

// ---------------------------------------------------------------------------
// GCN: 3x (GCNConv -> BatchNorm -> ReLU) -> fc1+ReLU -> fc2 -> log_softmax
// N=100000, E=1600000, IN=128, HID=64, classes=2.
// SINGLE persistent mega-kernel with device-wide barriers.
// R11 barrier fix (R9: RMW-spin storm; R10: acquire-load-spin = invalidate
// storm): RELAXED poll + single acquire fence on exit, and a 2-level arrival
// tree (32 groups x 32 blocks; same-line RMWs 1024 -> 32).
// Co-residency: 1024 blocks x 256 thr, __launch_bounds__(256,4), LDS 34.8KB
// -> 4 blocks/CU exact. Poison-proof: MAGIC gate, reset at end.
// ---------------------------------------------------------------------------

#define NBLK 1024
#define NTHR 256
#define BUCK_CAP 6144
#define PART_CHUNK 4096
#define MAGIC 0x7E57C0DE
#define BAR_STRIDE 528   // ints per barrier slot: 33 counters x 16-int spacing
#define NBAR 9

typedef _Float16 f16x8 __attribute__((ext_vector_type(8)));
typedef float f32x4 __attribute__((ext_vector_type(4)));

union H4U { uint2 u; __half h[4]; };
union H8U { uint4 u; __half h[8]; };

__device__ inline uint2 pack4(float a, float b, float c, float d) {
    H4U t;
    t.h[0] = __float2half_rn(a); t.h[1] = __float2half_rn(b);
    t.h[2] = __float2half_rn(c); t.h[3] = __float2half_rn(d);
    return t.u;
}
__device__ inline float4 unpack4(uint2 u) {
    H4U t; t.u = u;
    return make_float4(__half2float(t.h[0]), __half2float(t.h[1]),
                       __half2float(t.h[2]), __half2float(t.h[3]));
}
__device__ inline void upadd8(uint4 u, float* a) {
    H8U t; t.u = u;
#pragma unroll
    for (int i = 0; i < 8; ++i) a[i] += __half2float(t.h[i]);
}

// Device-wide barrier, 2-level tree. Counters: bar[0]=root, bar[(g+1)*16]=grp g.
// Arrivals: RELAXED RMW (release fence issued once, before). Poll: RELAXED
// load (no invalidate!) + one acquire fence after exit.
__device__ __forceinline__ void gbar(int* bars, int idx) {
    __syncthreads();
    if (threadIdx.x == 0) {
        int* bar = bars + idx * BAR_STRIDE;
        const int g = blockIdx.x >> 5;  // 32 groups of 32 blocks
        __threadfence();  // release: drain this block's writes
        int prev = __hip_atomic_fetch_add(&bar[(g + 1) * 16], 1,
                                          __ATOMIC_RELAXED,
                                          __HIP_MEMORY_SCOPE_AGENT);
        if (prev == 31)
            __hip_atomic_fetch_add(&bar[0], 1, __ATOMIC_RELAXED,
                                   __HIP_MEMORY_SCOPE_AGENT);
        while (__hip_atomic_load(&bar[0], __ATOMIC_RELAXED,
                                 __HIP_MEMORY_SCOPE_AGENT) < 32)
            __builtin_amdgcn_s_sleep(8);
        __threadfence();  // acquire: one invalidate, after barrier met
    }
    __syncthreads();
}

// ---- Phase: bucket partition (bucket = dst>>8), 4096-edge chunks ----------
__device__ void ph_part(char* sm, const int* __restrict__ src,
                        const int* __restrict__ dst, int* __restrict__ gcur,
                        unsigned* __restrict__ rec, int E, int NB) {
    int* hist = (int*)sm;        // 512 ints
    int* gbase = hist + 512;     // 512 ints
    const int tid = threadIdx.x;
    for (int chunk = blockIdx.x; chunk * PART_CHUNK < E; chunk += gridDim.x) {
        const int e0 = chunk * PART_CHUNK;
        const int e1 = min(e0 + PART_CHUNK, E);
        hist[tid] = 0; hist[tid + 256] = 0;
        __syncthreads();
        for (int i = e0 + tid; i < e1; i += 256)
            atomicAdd(&hist[dst[i] >> 8], 1);
        __syncthreads();
        for (int b = tid; b < NB; b += 256) {
            int c = hist[b];
            gbase[b] = c ? atomicAdd(&gcur[b], c) : 0;
            hist[b] = 0;  // reuse as cursor
        }
        __syncthreads();
        for (int i = e0 + tid; i < e1; i += 256) {
            int d = dst[i], s = src[i];
            int b = d >> 8;
            int off = atomicAdd(&hist[b], 1);
            rec[(size_t)b * BUCK_CAP + gbase[b] + off] =
                ((unsigned)s << 8) | (unsigned)(d & 255);
        }
        __syncthreads();
    }
}

// ---- Phase: per-bucket hist+scan+scatter -> dis, row_ptr, ssrc ------------
__device__ void ph_bscat(char* sm, const int* __restrict__ gcur,
                         const unsigned* __restrict__ rec,
                         float* __restrict__ dis, int* __restrict__ row_ptr,
                         int* __restrict__ ssrc, int n, int NB, int E) {
    if ((int)blockIdx.x >= NB) return;  // no barriers inside: safe
    int* h     = (int*)sm;        // 256
    int* cur   = h + 256;         // 256
    int* lb    = cur + 256;       // 512
    int* stmp  = lb + 512;        // 256
    int* stage = stmp + 256;      // 6144 (24 KB)
    const int b = blockIdx.x, tid = threadIdx.x;
    int g0 = (2 * tid < NB) ? gcur[2 * tid] : 0;
    int g1 = (2 * tid + 1 < NB) ? gcur[2 * tid + 1] : 0;
    int ps = g0 + g1;
    stmp[tid] = ps;
    h[tid] = 0;
    __syncthreads();
    int xx = ps;
    for (int off = 1; off < 256; off <<= 1) {
        int y = (tid >= off) ? stmp[tid - off] : 0;
        __syncthreads();
        xx += y;
        stmp[tid] = xx;
        __syncthreads();
    }
    int ex = xx - ps;
    lb[2 * tid] = ex;
    lb[2 * tid + 1] = ex + g0;
    __syncthreads();
    const int bb = lb[b];
    if (b == 0 && tid == 0) row_ptr[n] = E;

    const int cnt = gcur[b];
    const unsigned* r = rec + (size_t)b * BUCK_CAP;
    for (int i = tid; i < cnt; i += 256) {
        unsigned v = r[i];
        stage[i] = (int)v;  // stash to avoid global re-read
        atomicAdd(&h[v & 255u], 1);
    }
    __syncthreads();
    const int myd = h[tid];
    const int node = b * 256 + tid;
    if (node < n) dis[node] = rsqrtf((float)myd + 1.0f);  // self-loop degree
    int x = myd;
    for (int off = 1; off < 256; off <<= 1) {
        int y = (tid >= off) ? h[tid - off] : 0;
        __syncthreads();
        x += y;
        h[tid] = x;
        __syncthreads();
    }
    const int excl = x - myd;
    if (node < n) row_ptr[node] = bb + excl;
    cur[tid] = bb + excl;
    __syncthreads();
    for (int i = tid; i < cnt; i += 256) {
        unsigned v = (unsigned)stage[i];
        int pos = atomicAdd(&cur[v & 255u], 1);
        ssrc[pos] = (int)(v >> 8);
    }
}

// ---- Phase: MFMA GEMM, grid-strided 64-row tiles --------------------------
template <int K, bool BN, bool XH>
__device__ void ph_gemm(char* sm, const void* __restrict__ Xv,
                        const float* __restrict__ W,
                        const float* __restrict__ dis,
                        const float* __restrict__ stats,
                        const float* __restrict__ g,
                        const float* __restrict__ be,
                        __half* __restrict__ Hp, int n) {
    constexpr int KS = K / 32;
    constexpr int XSTR = K + 8;
    __half* BF = (__half*)sm;                 // KS*4*64*8 halves
    __half* XL = BF + KS * 4 * 64 * 8;        // 64*XSTR halves
    float* muS = (float*)(XL + 64 * XSTR);
    float* wS = muS + 64;
    float* bS = wS + 64;
    const int tid = threadIdx.x;

    if constexpr (BN) {
        if (tid < 64) {
            float s1 = 0.f, s2 = 0.f;
#pragma unroll
            for (int r = 0; r < 8; ++r) {
                s1 += stats[r * 128 + tid];
                s2 += stats[r * 128 + 64 + tid];
            }
            float inv_n = 1.0f / (float)n;
            float m = s1 * inv_n;
            float var = s2 * inv_n - m * m;
            muS[tid] = m;
            wS[tid] = rsqrtf(var + 1e-5f) * g[tid];
            bS[tid] = be[tid];
        }
    }
    for (int i = tid; i < KS * 4 * 64; i += 256) {
        int l = i & 63, fs = i >> 6;
        int ks = fs >> 2, ct = fs & 3;
        int kb = ks * 32 + ((l >> 4) << 3);
        int c = (ct << 4) + (l & 15);
        H8U t;
#pragma unroll
        for (int j = 0; j < 8; ++j) t.h[j] = __float2half_rn(W[(kb + j) * 64 + c]);
        *reinterpret_cast<uint4*>(&BF[i * 8]) = t.u;
    }
    __syncthreads();

    const int wave = tid >> 6, lane = tid & 63;
    const int ntiles = (n + 63) >> 6;
    for (int t = blockIdx.x; t < ntiles; t += gridDim.x) {
        const int row0 = t * 64;
        __syncthreads();  // previous tile's XL readers done
        if constexpr (!XH) {
            constexpr int Q4 = K / 4;
            const float4* X4 = (const float4*)Xv;
            for (int it = 0; it < 64 * Q4 / 256; ++it) {
                int idx = it * 256 + tid;
                int row = idx / Q4, q = idx % Q4;
                int grow = row0 + row;
                float4 v = make_float4(0.f, 0.f, 0.f, 0.f);
                if (grow < n) v = X4[(size_t)grow * Q4 + q];
                *reinterpret_cast<uint2*>(&XL[row * XSTR + q * 4]) =
                    pack4(v.x, v.y, v.z, v.w);
            }
        } else {
            constexpr int QU = K / 4;
            const uint2* Xh = (const uint2*)Xv;
            for (int it = 0; it < 64 * QU / 256; ++it) {
                int idx = it * 256 + tid;
                int row = idx / QU, q = idx % QU;
                int grow = row0 + row;
                float4 v = make_float4(0.f, 0.f, 0.f, 0.f);
                if (grow < n) {
                    v = unpack4(Xh[(size_t)grow * QU + q]);
                    float4 m = *reinterpret_cast<const float4*>(&muS[q * 4]);
                    float4 w4 = *reinterpret_cast<const float4*>(&wS[q * 4]);
                    float4 b4 = *reinterpret_cast<const float4*>(&bS[q * 4]);
                    v.x = fmaxf((v.x - m.x) * w4.x + b4.x, 0.f);
                    v.y = fmaxf((v.y - m.y) * w4.y + b4.y, 0.f);
                    v.z = fmaxf((v.z - m.z) * w4.z + b4.z, 0.f);
                    v.w = fmaxf((v.w - m.w) * w4.w + b4.w, 0.f);
                }
                *reinterpret_cast<uint2*>(&XL[row * XSTR + q * 4]) =
                    pack4(v.x, v.y, v.z, v.w);
            }
        }
        __syncthreads();

        const __half* arow = &XL[(wave * 16 + (lane & 15)) * XSTR + ((lane >> 4) << 3)];
        f16x8 a[KS];
#pragma unroll
        for (int ks = 0; ks < KS; ++ks)
            a[ks] = *reinterpret_cast<const f16x8*>(arow + ks * 32);

        f32x4 acc[4];
#pragma unroll
        for (int ct = 0; ct < 4; ++ct) acc[ct] = (f32x4){0.f, 0.f, 0.f, 0.f};
#pragma unroll
        for (int ct = 0; ct < 4; ++ct)
#pragma unroll
            for (int ks = 0; ks < KS; ++ks) {
                f16x8 b = *reinterpret_cast<const f16x8*>(
                    &BF[((ks * 4 + ct) * 64 + lane) * 8]);
                acc[ct] = __builtin_amdgcn_mfma_f32_16x16x32_f16(a[ks], b, acc[ct], 0, 0, 0);
            }

        const int mbase = row0 + wave * 16 + ((lane >> 4) << 2);
#pragma unroll
        for (int reg = 0; reg < 4; ++reg) {
            int grow = mbase + reg;
            if (grow < n) {
                float dd = dis[grow];
#pragma unroll
                for (int ct = 0; ct < 4; ++ct)
                    Hp[(size_t)grow * 64 + ct * 16 + (lane & 15)] =
                        __float2half_rn(acc[ct][reg] * dd);
            }
        }
    }
}

// ---- Phase: gather + fused BN stats ---------------------------------------
__device__ void ph_gather(char* sm, const int* __restrict__ row_ptr,
                          const int* __restrict__ ssrc,
                          const float* __restrict__ dis,
                          const uint4* __restrict__ Hp, uint4* __restrict__ AGG,
                          float* __restrict__ stats, int n) {
    float* red1 = (float*)sm;     // [32][64]
    float* red2 = red1 + 2048;    // [32][64]
    const int tid = threadIdx.x;
    const int g = tid >> 3, fi = tid & 7;
    float sacc[8] = {}, qacc[8] = {};
    for (int d = blockIdx.x * 32 + g; d < n; d += gridDim.x * 32) {
        int r0 = row_ptr[d], r1 = row_ptr[d + 1];
        float a[8] = {};
        upadd8(Hp[(size_t)d * 8 + fi], a);  // self-loop contribution
        int p = r0;
        for (; p + 7 < r1; p += 8) {
            int s0 = ssrc[p], s1 = ssrc[p + 1], s2 = ssrc[p + 2], s3 = ssrc[p + 3];
            int s4 = ssrc[p + 4], s5 = ssrc[p + 5], s6 = ssrc[p + 6], s7 = ssrc[p + 7];
            uint4 q0 = Hp[(size_t)s0 * 8 + fi];
            uint4 q1 = Hp[(size_t)s1 * 8 + fi];
            uint4 q2 = Hp[(size_t)s2 * 8 + fi];
            uint4 q3 = Hp[(size_t)s3 * 8 + fi];
            uint4 q4 = Hp[(size_t)s4 * 8 + fi];
            uint4 q5 = Hp[(size_t)s5 * 8 + fi];
            uint4 q6 = Hp[(size_t)s6 * 8 + fi];
            uint4 q7 = Hp[(size_t)s7 * 8 + fi];
            upadd8(q0, a); upadd8(q1, a); upadd8(q2, a); upadd8(q3, a);
            upadd8(q4, a); upadd8(q5, a); upadd8(q6, a); upadd8(q7, a);
        }
        for (; p + 3 < r1; p += 4) {
            int s0 = ssrc[p], s1 = ssrc[p + 1], s2 = ssrc[p + 2], s3 = ssrc[p + 3];
            uint4 q0 = Hp[(size_t)s0 * 8 + fi];
            uint4 q1 = Hp[(size_t)s1 * 8 + fi];
            uint4 q2 = Hp[(size_t)s2 * 8 + fi];
            uint4 q3 = Hp[(size_t)s3 * 8 + fi];
            upadd8(q0, a); upadd8(q1, a); upadd8(q2, a); upadd8(q3, a);
        }
        for (; p < r1; ++p) upadd8(Hp[(size_t)ssrc[p] * 8 + fi], a);
        float dd = dis[d];
        H8U o;
#pragma unroll
        for (int i = 0; i < 8; ++i) {
            float v = a[i] * dd;
            o.h[i] = __float2half_rn(v);
            sacc[i] += v;
            qacc[i] += v * v;
        }
        AGG[(size_t)d * 8 + fi] = o.u;
    }
#pragma unroll
    for (int j = 0; j < 8; ++j) {
        red1[g * 64 + fi * 8 + j] = sacc[j];
        red2[g * 64 + fi * 8 + j] = qacc[j];
    }
    __syncthreads();
    if (tid < 64) {
        float s = 0.f;
#pragma unroll
        for (int r = 0; r < 32; ++r) s += red1[r * 64 + tid];
        atomicAdd(&stats[(blockIdx.x & 7) * 128 + tid], s);
    } else if (tid < 128) {
        int f = tid - 64;
        float s = 0.f;
#pragma unroll
        for (int r = 0; r < 32; ++r) s += red2[r * 64 + f];
        atomicAdd(&stats[(blockIdx.x & 7) * 128 + 64 + f], s);
    }
    __syncthreads();  // red reuse safety for next phase using pool
}

// ---- Phase: head ----------------------------------------------------------
__device__ void ph_head(char* sm, const uint2* __restrict__ X,
                        const float* __restrict__ stats,
                        const float* __restrict__ g, const float* __restrict__ be,
                        const float* __restrict__ w1, const float* __restrict__ b1,
                        const float* __restrict__ w2, const float* __restrict__ b2,
                        float* __restrict__ out, int n) {
    float* w1s = (float*)sm;        // 2048
    float* muS = w1s + 2048;        // 64
    float* wS = muS + 64;
    float* bS = wS + 64;
    float* b1s = bS + 64;           // 32
    float* w2s = b1s + 32;          // 64
    float* b2s = w2s + 64;          // 2
    int tid = threadIdx.x;
    for (int i = tid; i < 512; i += 256)
        reinterpret_cast<float4*>(w1s)[i] = reinterpret_cast<const float4*>(w1)[i];
    if (tid < 32) b1s[tid] = b1[tid];
    if (tid >= 64 && tid < 128) w2s[tid - 64] = w2[tid - 64];
    if (tid >= 128 && tid < 130) b2s[tid - 128] = b2[tid - 128];
    if (tid < 64) {
        float s1 = 0.f, s2 = 0.f;
#pragma unroll
        for (int r = 0; r < 8; ++r) {
            s1 += stats[r * 128 + tid];
            s2 += stats[r * 128 + 64 + tid];
        }
        float inv_n = 1.0f / (float)n;
        float m = s1 * inv_n;
        float var = s2 * inv_n - m * m;
        muS[tid] = m;
        wS[tid] = rsqrtf(var + 1e-5f) * g[tid];
        bS[tid] = be[tid];
    }
    __syncthreads();
    for (int row = blockIdx.x * NTHR + tid; row < n; row += gridDim.x * NTHR) {
        float4 h[8];
#pragma unroll
        for (int j4 = 0; j4 < 8; ++j4) h[j4] = reinterpret_cast<float4*>(b1s)[j4];
#pragma unroll
        for (int k4 = 0; k4 < 16; ++k4) {
            float4 xv = unpack4(X[(size_t)row * 16 + k4]);
#pragma unroll
            for (int kk = 0; kk < 4; ++kk) {
                int k = k4 * 4 + kk;
                float raw = (kk == 0) ? xv.x : (kk == 1) ? xv.y : (kk == 2) ? xv.z : xv.w;
                float xk = fmaxf((raw - muS[k]) * wS[k] + bS[k], 0.f);
                const float4* wrow = reinterpret_cast<const float4*>(&w1s[k * 32]);
#pragma unroll
                for (int j4 = 0; j4 < 8; ++j4) {
                    float4 wv = wrow[j4];
                    h[j4].x += xk * wv.x; h[j4].y += xk * wv.y;
                    h[j4].z += xk * wv.z; h[j4].w += xk * wv.w;
                }
            }
        }
        float o0 = b2s[0], o1 = b2s[1];
#pragma unroll
        for (int j4 = 0; j4 < 8; ++j4) {
            float hv[4] = {h[j4].x, h[j4].y, h[j4].z, h[j4].w};
#pragma unroll
            for (int c = 0; c < 4; ++c) {
                float hj = fmaxf(hv[c], 0.f);
                int j = j4 * 4 + c;
                o0 += hj * w2s[2 * j];
                o1 += hj * w2s[2 * j + 1];
            }
        }
        float m = fmaxf(o0, o1);
        float l = __logf(__expf(o0 - m) + __expf(o1 - m));
        reinterpret_cast<float2*>(out)[row] = make_float2(o0 - m - l, o1 - m - l);
    }
}

// ---- The mega-kernel ------------------------------------------------------
__global__ __launch_bounds__(NTHR, 4) void k_mega(
    const float* __restrict__ x, const int* __restrict__ src,
    const int* __restrict__ dst,
    const float* W0, const float* W1, const float* W2,
    const float* g0, const float* be0, const float* g1, const float* be1,
    const float* g2, const float* be2,
    const float* fc1w, const float* fc1b, const float* fc2w, const float* fc2b,
    float* out,
    int* ctrl, int* gcur, float* stats, float* dis, int* row_ptr,
    unsigned* rec, int* ssrc, __half* B0, __half* B1,
    int n, int E, int NB) {
    __shared__ __align__(16) char sm[34816];
    int* A = ctrl;            // gate flag
    int* bars = ctrl + 64;    // NBAR x BAR_STRIDE tree-barrier counters

    // P0: block0 init (barrier counters, gcur, stats) then release gate.
    if (blockIdx.x == 0) {
        int t = threadIdx.x;
        for (int i = t; i < NBAR * BAR_STRIDE; i += 256) bars[i] = 0;
        gcur[t] = 0; gcur[t + 256] = 0;
#pragma unroll
        for (int k = 0; k < 12; ++k) stats[k * 256 + t] = 0.f;
        __syncthreads();
        if (t == 0) {
            __threadfence();
            __hip_atomic_store(A, MAGIC, __ATOMIC_RELEASE, __HIP_MEMORY_SCOPE_AGENT);
        }
    }
    if (threadIdx.x == 0) {
        while (__hip_atomic_load(A, __ATOMIC_RELAXED,
                                 __HIP_MEMORY_SCOPE_AGENT) != MAGIC)
            __builtin_amdgcn_s_sleep(8);
        __threadfence();
    }
    __syncthreads();

    ph_part(sm, src, dst, gcur, rec, E, NB);
    gbar(bars, 0);
    ph_bscat(sm, gcur, rec, dis, row_ptr, ssrc, n, NB, E);
    gbar(bars, 1);
    ph_gemm<128, false, false>(sm, x, W0, dis, nullptr, nullptr, nullptr, B0, n);
    gbar(bars, 2);
    ph_gather(sm, row_ptr, ssrc, dis, (const uint4*)B0, (uint4*)B1, stats + 0, n);
    gbar(bars, 3);
    ph_gemm<64, true, true>(sm, B1, W1, dis, stats + 0, g0, be0, B0, n);
    gbar(bars, 4);
    ph_gather(sm, row_ptr, ssrc, dis, (const uint4*)B0, (uint4*)B1, stats + 1024, n);
    gbar(bars, 5);
    ph_gemm<64, true, true>(sm, B1, W2, dis, stats + 1024, g1, be1, B0, n);
    gbar(bars, 6);
    ph_gather(sm, row_ptr, ssrc, dis, (const uint4*)B0, (uint4*)B1, stats + 2048, n);
    gbar(bars, 7);
    ph_head(sm, (const uint2*)B1, stats + 2048, g2, be2, fc1w, fc1b, fc2w, fc2b,
            out, n);
    gbar(bars, 8);
    if (blockIdx.x == 0 && threadIdx.x == 0)
        __hip_atomic_store(A, 0, __ATOMIC_RELEASE, __HIP_MEMORY_SCOPE_AGENT);
}

extern "C" void kernel_launch(void* const* d_in, const int* in_sizes, int n_in,
                              void* d_out, int out_size, void* d_ws, size_t ws_size,
                              hipStream_t stream) {
    const float* x    = (const float*)d_in[0];
    const int*   ei   = (const int*)d_in[1];
    const float* W0   = (const float*)d_in[2];
    const float* W1   = (const float*)d_in[4];
    const float* W2   = (const float*)d_in[6];
    const float* g0   = (const float*)d_in[8];
    const float* be0  = (const float*)d_in[9];
    const float* g1   = (const float*)d_in[10];
    const float* be1  = (const float*)d_in[11];
    const float* g2   = (const float*)d_in[12];
    const float* be2  = (const float*)d_in[13];
    const float* fc1w = (const float*)d_in[14];
    const float* fc1b = (const float*)d_in[15];
    const float* fc2w = (const float*)d_in[16];
    const float* fc2b = (const float*)d_in[17];

    const int N = in_sizes[0] / 128;
    const int E = in_sizes[1] / 2;
    const int* srcp = ei;
    const int* dstp = ei + E;
    const int NB = (N + 255) >> 8;  // 256-node buckets (<=512)

    char* ws = (char*)d_ws;
    size_t off = 0;
    auto alloc = [&](size_t bytes) -> void* {
        void* p = ws + off;
        off = (off + bytes + 255) & ~(size_t)255;
        return p;
    };
    int*      ctrl    = (int*)alloc((64 + NBAR * BAR_STRIDE) * 4);
    int*      gcur    = (int*)alloc(512 * 4);
    float*    stats   = (float*)alloc(3 * 8 * 128 * 4);
    float*    dis     = (float*)alloc((size_t)N * 4);
    int*      row_ptr = (int*)alloc((size_t)(N + 1) * 4);
    unsigned* rec     = (unsigned*)alloc((size_t)NB * BUCK_CAP * 4);
    int*      ssrc    = (int*)alloc((size_t)E * 4);
    __half*   B0      = (__half*)alloc((size_t)N * 64 * 2);
    __half*   B1      = (__half*)alloc((size_t)N * 64 * 2);

    k_mega<<<NBLK, NTHR, 0, stream>>>(
        x, srcp, dstp, W0, W1, W2, g0, be0, g1, be1, g2, be2,
        fc1w, fc1b, fc2w, fc2b, (float*)d_out,
        ctrl, gcur, stats, dis, row_ptr, rec, ssrc, B0, B1, N, E, NB);
}

// Round 12
// 214.366 us; speedup vs baseline: 22.8953x; 4.0094x over previous
//
#include <hip/hip_runtime.h>
#include <hip/hip_fp16.h>
#include <math.h>

// ---------------------------------------------------------------------------
// GCN: 3x (GCNConv -> BatchNorm -> ReLU) -> fc1+ReLU -> fc2 -> log_softmax
// N=100000, E=1600000, IN=128, HID=64, classes=2.
// Conv biases cancel through BN mean-subtraction -> skipped.
// GEMMs: v_mfma_f32_16x16x32_f16 (fp16 in, fp32 accum).
// CSR per call: bucket partition (reserved-run direct writes) -> per-bucket
// hist+scan+scatter. Hp/AGG fp16; BN-apply+ReLU fused into consumer;
// BN stats fused into gather epilogue (8-replica atomics).
// R12: mega-kernel (R9-R11) falsified — sw-barrier coherence cost ~70us/phase
// vs ~6us/HW dispatch. Reverted to R8 multi-dispatch; k_zero folded into
// k_part via MAGIC gate (block 0 zeroes gcur+stats, others overlap their LDS
// histogram then spin relaxed; 196 blocks co-resident). 9 dispatches.
// ---------------------------------------------------------------------------

#define BUCK_CAP 6144   // slots per 256-node bucket (mean 4096, +32 sigma)
#define PB_EDGES 8192   // edges per k_part block (16 per thread @ 512 thr)
#define MAGIC 0x7E57C0DE

typedef _Float16 f16x8 __attribute__((ext_vector_type(8)));
typedef float f32x4 __attribute__((ext_vector_type(4)));

union H4U { uint2 u; __half h[4]; };
union H8U { uint4 u; __half h[8]; };

__device__ inline uint2 pack4(float a, float b, float c, float d) {
    H4U t;
    t.h[0] = __float2half_rn(a); t.h[1] = __float2half_rn(b);
    t.h[2] = __float2half_rn(c); t.h[3] = __float2half_rn(d);
    return t.u;
}
__device__ inline float4 unpack4(uint2 u) {
    H4U t; t.u = u;
    return make_float4(__half2float(t.h[0]), __half2float(t.h[1]),
                       __half2float(t.h[2]), __half2float(t.h[3]));
}
__device__ inline void upadd8(uint4 u, float* a) {
    H8U t; t.u = u;
#pragma unroll
    for (int i = 0; i < 8; ++i) a[i] += __half2float(t.h[i]);
}

// Pass A + init: block 0 zeroes gcur (512 ints) + stats (3x8x128 floats) and
// releases gate; all blocks overlap their LDS histogram with that, then gate
// before the global reservation. Record = (src<<8)|(dst&255).
__global__ __launch_bounds__(512) void k_part(const int* __restrict__ src,
                                              const int* __restrict__ dst,
                                              int* __restrict__ gcur,
                                              float* __restrict__ stats,
                                              int* __restrict__ gate,
                                              unsigned* __restrict__ rec,
                                              int E, int NB) {
    __shared__ int hist[512];
    __shared__ int gbase[512];
    const int tid = threadIdx.x;

    if (blockIdx.x == 0) {
        gcur[tid] = 0;
        for (int i = tid; i < 3 * 8 * 128; i += 512) stats[i] = 0.f;
        __syncthreads();
        if (tid == 0) {
            __threadfence();
            __hip_atomic_store(gate, MAGIC, __ATOMIC_RELEASE,
                               __HIP_MEMORY_SCOPE_AGENT);
        }
    }

    const int e0 = blockIdx.x * PB_EDGES;
    const int e1 = min(e0 + PB_EDGES, E);
    hist[tid] = 0;
    __syncthreads();
    int dloc[PB_EDGES / 512];
#pragma unroll
    for (int it = 0; it < PB_EDGES / 512; ++it) {
        int i = e0 + it * 512 + tid;
        if (i < e1) {
            int d = dst[i];
            dloc[it] = d;
            atomicAdd(&hist[d >> 8], 1);
        } else dloc[it] = -1;
    }
    __syncthreads();
    // gate: gcur must be zeroed before reservation (relaxed poll, one fence)
    if (tid == 0) {
        while (__hip_atomic_load(gate, __ATOMIC_RELAXED,
                                 __HIP_MEMORY_SCOPE_AGENT) != MAGIC)
            __builtin_amdgcn_s_sleep(8);
        __threadfence();
    }
    __syncthreads();
    if (tid < NB) {
        int c = hist[tid];
        gbase[tid] = c ? atomicAdd(&gcur[tid], c) : 0;
    }
    __syncthreads();
    hist[tid] = 0;
    __syncthreads();
#pragma unroll
    for (int it = 0; it < PB_EDGES / 512; ++it) {
        int d = dloc[it];
        if (d >= 0) {
            int i = e0 + it * 512 + tid;
            int b = d >> 8;
            int s = src[i];
            int off = atomicAdd(&hist[b], 1);
            rec[(size_t)b * BUCK_CAP + gbase[b] + off] =
                ((unsigned)s << 8) | (unsigned)(d & 255);
        }
    }
}

// Pass B: per-bucket. Resets gate (stream order: all k_part blocks done).
// Recompute bucket prefix from gcur, node histogram -> dis + row_ptr, LDS
// scan, direct scatter into ssrc segment (L2-resident while filled).
__global__ __launch_bounds__(256) void k_bscat(const int* __restrict__ gcur,
                                               const unsigned* __restrict__ rec,
                                               float* __restrict__ dis,
                                               int* __restrict__ row_ptr,
                                               int* __restrict__ ssrc,
                                               int* __restrict__ gate,
                                               int n, int NB, int E) {
    __shared__ int h[256];
    __shared__ int cur[256];
    __shared__ int lb[512];
    __shared__ int stmp[256];
    const int b = blockIdx.x, tid = threadIdx.x;
    if (b == 0 && tid == 0)
        __hip_atomic_store(gate, 0, __ATOMIC_RELAXED, __HIP_MEMORY_SCOPE_AGENT);
    // bucket prefix: exclusive scan of gcur[0..NB-1]
    int g0 = (2 * tid < NB) ? gcur[2 * tid] : 0;
    int g1 = (2 * tid + 1 < NB) ? gcur[2 * tid + 1] : 0;
    int ps = g0 + g1;
    stmp[tid] = ps;
    h[tid] = 0;
    __syncthreads();
    int xx = ps;
    for (int off = 1; off < 256; off <<= 1) {
        int y = (tid >= off) ? stmp[tid - off] : 0;
        __syncthreads();
        xx += y;
        stmp[tid] = xx;
        __syncthreads();
    }
    int ex = xx - ps;
    lb[2 * tid] = ex;
    lb[2 * tid + 1] = ex + g0;
    __syncthreads();
    const int bb = lb[b];
    if (b == 0 && tid == 0) row_ptr[n] = E;

    const int cnt = gcur[b];
    const unsigned* r = rec + (size_t)b * BUCK_CAP;
    for (int i = tid; i < cnt; i += 256)
        atomicAdd(&h[r[i] & 255u], 1);
    __syncthreads();
    const int myd = h[tid];
    const int node = b * 256 + tid;
    if (node < n) dis[node] = rsqrtf((float)myd + 1.0f);  // self-loop degree
    int x = myd;
    for (int off = 1; off < 256; off <<= 1) {
        int y = (tid >= off) ? h[tid - off] : 0;
        __syncthreads();
        x += y;
        h[tid] = x;
        __syncthreads();
    }
    const int excl = x - myd;
    if (node < n) row_ptr[node] = bb + excl;
    cur[tid] = bb + excl;  // global cursor
    __syncthreads();
    for (int i = tid; i < cnt; i += 256) {
        unsigned v = r[i];
        int pos = atomicAdd(&cur[v & 255u], 1);
        ssrc[pos] = (int)(v >> 8);
    }
}

// MFMA GEMM: Hp[n,64] = (BN?(X)[n,K] @ W[K,64]) * dis[row], fp16 out, f32 accum.
// stats layout when BN: 8 replicas x (64 sum | 64 sumsq).
template <int K, bool BN, bool XH>
__global__ __launch_bounds__(256) void k_gemm(const void* __restrict__ Xv,
                                              const float* __restrict__ W,
                                              const float* __restrict__ dis,
                                              const float* __restrict__ stats,
                                              const float* __restrict__ g,
                                              const float* __restrict__ be,
                                              __half* __restrict__ Hp, int n) {
    constexpr int KS = K / 32;        // mfma k-steps
    constexpr int XSTR = K + 8;       // padded LDS row stride (halves)
    __shared__ __align__(16) __half BF[KS * 4 * 64 * 8];  // B frags, lane-contig
    __shared__ __align__(16) __half XL[64 * XSTR];
    __shared__ float muS[64], wS[64], bS[64];
    const int tid = threadIdx.x;
    const int row0 = blockIdx.x * 64;

    if constexpr (BN) {
        if (tid < 64) {
            float s1 = 0.f, s2 = 0.f;
#pragma unroll
            for (int r = 0; r < 8; ++r) {
                s1 += stats[r * 128 + tid];
                s2 += stats[r * 128 + 64 + tid];
            }
            float inv_n = 1.0f / (float)n;
            float m = s1 * inv_n;
            float var = s2 * inv_n - m * m;
            muS[tid] = m;
            wS[tid] = rsqrtf(var + 1e-5f) * g[tid];
            bS[tid] = be[tid];
        }
    }
    // Build per-lane B fragments from W (global, L2-hot)
    for (int i = tid; i < KS * 4 * 64; i += 256) {
        int l = i & 63, fs = i >> 6;
        int ks = fs >> 2, ct = fs & 3;
        int kb = ks * 32 + ((l >> 4) << 3);
        int c = (ct << 4) + (l & 15);
        H8U t;
#pragma unroll
        for (int j = 0; j < 8; ++j) t.h[j] = __float2half_rn(W[(kb + j) * 64 + c]);
        *reinterpret_cast<uint4*>(&BF[i * 8]) = t.u;
    }
    __syncthreads();  // BF + BN consts visible

    if constexpr (!XH) {
        constexpr int Q4 = K / 4;
        const float4* X4 = (const float4*)Xv;
        for (int it = 0; it < 64 * Q4 / 256; ++it) {
            int idx = it * 256 + tid;
            int row = idx / Q4, q = idx % Q4;
            int grow = row0 + row;
            float4 v = make_float4(0.f, 0.f, 0.f, 0.f);
            if (grow < n) v = X4[(size_t)grow * Q4 + q];
            *reinterpret_cast<uint2*>(&XL[row * XSTR + q * 4]) = pack4(v.x, v.y, v.z, v.w);
        }
    } else {
        constexpr int QU = K / 4;
        const uint2* Xh = (const uint2*)Xv;
        for (int it = 0; it < 64 * QU / 256; ++it) {
            int idx = it * 256 + tid;
            int row = idx / QU, q = idx % QU;
            int grow = row0 + row;
            float4 v = make_float4(0.f, 0.f, 0.f, 0.f);
            if (grow < n) {
                v = unpack4(Xh[(size_t)grow * QU + q]);
                float4 m = *reinterpret_cast<const float4*>(&muS[q * 4]);
                float4 w4 = *reinterpret_cast<const float4*>(&wS[q * 4]);
                float4 b4 = *reinterpret_cast<const float4*>(&bS[q * 4]);
                v.x = fmaxf((v.x - m.x) * w4.x + b4.x, 0.f);
                v.y = fmaxf((v.y - m.y) * w4.y + b4.y, 0.f);
                v.z = fmaxf((v.z - m.z) * w4.z + b4.z, 0.f);
                v.w = fmaxf((v.w - m.w) * w4.w + b4.w, 0.f);
            }
            *reinterpret_cast<uint2*>(&XL[row * XSTR + q * 4]) = pack4(v.x, v.y, v.z, v.w);
        }
    }
    __syncthreads();

    const int wave = tid >> 6, lane = tid & 63;
    const __half* arow = &XL[(wave * 16 + (lane & 15)) * XSTR + ((lane >> 4) << 3)];
    f16x8 a[KS];
#pragma unroll
    for (int ks = 0; ks < KS; ++ks)
        a[ks] = *reinterpret_cast<const f16x8*>(arow + ks * 32);

    f32x4 acc[4];
#pragma unroll
    for (int ct = 0; ct < 4; ++ct) acc[ct] = (f32x4){0.f, 0.f, 0.f, 0.f};
#pragma unroll
    for (int ct = 0; ct < 4; ++ct)
#pragma unroll
        for (int ks = 0; ks < KS; ++ks) {
            f16x8 b = *reinterpret_cast<const f16x8*>(&BF[((ks * 4 + ct) * 64 + lane) * 8]);
            acc[ct] = __builtin_amdgcn_mfma_f32_16x16x32_f16(a[ks], b, acc[ct], 0, 0, 0);
        }

    const int mbase = row0 + wave * 16 + ((lane >> 4) << 2);
#pragma unroll
    for (int reg = 0; reg < 4; ++reg) {
        int grow = mbase + reg;
        if (grow < n) {
            float dd = dis[grow];
#pragma unroll
            for (int ct = 0; ct < 4; ++ct)
                Hp[(size_t)grow * 64 + ct * 16 + (lane & 15)] =
                    __float2half_rn(acc[ct][reg] * dd);
        }
    }
}

// Gather + fused BN stats: AGG[d] = dis[d] * (Hp[d] + sum_{s in N(d)} Hp[s]).
// 8 lanes/node x uint4, fixed grid (grid-stride over 32-node groups).
// Epilogue: per-block LDS reduce of sum/sumsq -> atomicAdd into replica
// stats[(blockIdx&7)*128 + {f | 64+f}].
__global__ __launch_bounds__(256) void k_gather(const int* __restrict__ row_ptr,
                                                const int* __restrict__ ssrc,
                                                const float* __restrict__ dis,
                                                const uint4* __restrict__ Hp,
                                                uint4* __restrict__ AGG,
                                                float* __restrict__ stats, int n) {
    __shared__ float red[32][64];  // 8 KB, reused for sum then sumsq
    const int tid = threadIdx.x;
    const int g = tid >> 3, fi = tid & 7;
    float sacc[8] = {}, qacc[8] = {};
    for (int d = blockIdx.x * 32 + g; d < n; d += gridDim.x * 32) {
        int r0 = row_ptr[d], r1 = row_ptr[d + 1];
        float a[8] = {};
        upadd8(Hp[(size_t)d * 8 + fi], a);  // self-loop contribution
        int p = r0;
        for (; p + 7 < r1; p += 8) {
            int s0 = ssrc[p], s1 = ssrc[p + 1], s2 = ssrc[p + 2], s3 = ssrc[p + 3];
            int s4 = ssrc[p + 4], s5 = ssrc[p + 5], s6 = ssrc[p + 6], s7 = ssrc[p + 7];
            uint4 q0 = Hp[(size_t)s0 * 8 + fi];
            uint4 q1 = Hp[(size_t)s1 * 8 + fi];
            uint4 q2 = Hp[(size_t)s2 * 8 + fi];
            uint4 q3 = Hp[(size_t)s3 * 8 + fi];
            uint4 q4 = Hp[(size_t)s4 * 8 + fi];
            uint4 q5 = Hp[(size_t)s5 * 8 + fi];
            uint4 q6 = Hp[(size_t)s6 * 8 + fi];
            uint4 q7 = Hp[(size_t)s7 * 8 + fi];
            upadd8(q0, a); upadd8(q1, a); upadd8(q2, a); upadd8(q3, a);
            upadd8(q4, a); upadd8(q5, a); upadd8(q6, a); upadd8(q7, a);
        }
        for (; p + 3 < r1; p += 4) {
            int s0 = ssrc[p], s1 = ssrc[p + 1], s2 = ssrc[p + 2], s3 = ssrc[p + 3];
            uint4 q0 = Hp[(size_t)s0 * 8 + fi];
            uint4 q1 = Hp[(size_t)s1 * 8 + fi];
            uint4 q2 = Hp[(size_t)s2 * 8 + fi];
            uint4 q3 = Hp[(size_t)s3 * 8 + fi];
            upadd8(q0, a); upadd8(q1, a); upadd8(q2, a); upadd8(q3, a);
        }
        for (; p < r1; ++p) upadd8(Hp[(size_t)ssrc[p] * 8 + fi], a);
        float dd = dis[d];
        H8U o;
#pragma unroll
        for (int i = 0; i < 8; ++i) {
            float v = a[i] * dd;
            o.h[i] = __float2half_rn(v);
            sacc[i] += v;
            qacc[i] += v * v;
        }
        AGG[(size_t)d * 8 + fi] = o.u;
    }
    // block reduce -> replica atomics
#pragma unroll
    for (int j = 0; j < 8; ++j) red[g][fi * 8 + j] = sacc[j];
    __syncthreads();
    if (tid < 64) {
        float s = 0.f;
#pragma unroll
        for (int r = 0; r < 32; ++r) s += red[r][tid];
        atomicAdd(&stats[(blockIdx.x & 7) * 128 + tid], s);
    }
    __syncthreads();
#pragma unroll
    for (int j = 0; j < 8; ++j) red[g][fi * 8 + j] = qacc[j];
    __syncthreads();
    if (tid < 64) {
        float s = 0.f;
#pragma unroll
        for (int r = 0; r < 32; ++r) s += red[r][tid];
        atomicAdd(&stats[(blockIdx.x & 7) * 128 + 64 + tid], s);
    }
}

// Head: relu(BN(X)) -> relu(@w1+b1) -> @w2+b2 -> log_softmax. One thread/row.
__global__ __launch_bounds__(256) void k_head(const uint2* __restrict__ X,
                                              const float* __restrict__ stats,
                                              const float* __restrict__ g,
                                              const float* __restrict__ be,
                                              const float* __restrict__ w1,
                                              const float* __restrict__ b1,
                                              const float* __restrict__ w2,
                                              const float* __restrict__ b2,
                                              float* __restrict__ out, int n) {
    __shared__ __align__(16) float w1s[64 * 32];
    __shared__ __align__(16) float b1s[32];
    __shared__ float w2s[64];
    __shared__ float b2s[2];
    __shared__ float muS[64], wS[64], bS[64];
    int tid = threadIdx.x;
    for (int i = tid; i < 512; i += 256)
        reinterpret_cast<float4*>(w1s)[i] = reinterpret_cast<const float4*>(w1)[i];
    if (tid < 32) b1s[tid] = b1[tid];
    if (tid >= 64 && tid < 128) w2s[tid - 64] = w2[tid - 64];
    if (tid >= 128 && tid < 130) b2s[tid - 128] = b2[tid - 128];
    if (tid < 64) {
        float s1 = 0.f, s2 = 0.f;
#pragma unroll
        for (int r = 0; r < 8; ++r) {
            s1 += stats[r * 128 + tid];
            s2 += stats[r * 128 + 64 + tid];
        }
        float inv_n = 1.0f / (float)n;
        float m = s1 * inv_n;
        float var = s2 * inv_n - m * m;
        muS[tid] = m;
        wS[tid] = rsqrtf(var + 1e-5f) * g[tid];
        bS[tid] = be[tid];
    }
    __syncthreads();
    int row = blockIdx.x * 256 + tid;
    if (row >= n) return;

    float4 h[8];
#pragma unroll
    for (int j4 = 0; j4 < 8; ++j4) h[j4] = reinterpret_cast<float4*>(b1s)[j4];

#pragma unroll
    for (int k4 = 0; k4 < 16; ++k4) {
        float4 xv = unpack4(X[(size_t)row * 16 + k4]);
#pragma unroll
        for (int kk = 0; kk < 4; ++kk) {
            int k = k4 * 4 + kk;
            float raw = (kk == 0) ? xv.x : (kk == 1) ? xv.y : (kk == 2) ? xv.z : xv.w;
            float xk = fmaxf((raw - muS[k]) * wS[k] + bS[k], 0.f);
            const float4* wrow = reinterpret_cast<const float4*>(&w1s[k * 32]);
#pragma unroll
            for (int j4 = 0; j4 < 8; ++j4) {
                float4 wv = wrow[j4];
                h[j4].x += xk * wv.x; h[j4].y += xk * wv.y;
                h[j4].z += xk * wv.z; h[j4].w += xk * wv.w;
            }
        }
    }
    float o0 = b2s[0], o1 = b2s[1];
#pragma unroll
    for (int j4 = 0; j4 < 8; ++j4) {
        float hv[4] = {h[j4].x, h[j4].y, h[j4].z, h[j4].w};
#pragma unroll
        for (int c = 0; c < 4; ++c) {
            float hj = fmaxf(hv[c], 0.f);
            int j = j4 * 4 + c;
            o0 += hj * w2s[2 * j];
            o1 += hj * w2s[2 * j + 1];
        }
    }
    float m = fmaxf(o0, o1);
    float l = __logf(__expf(o0 - m) + __expf(o1 - m));
    reinterpret_cast<float2*>(out)[row] = make_float2(o0 - m - l, o1 - m - l);
}

extern "C" void kernel_launch(void* const* d_in, const int* in_sizes, int n_in,
                              void* d_out, int out_size, void* d_ws, size_t ws_size,
                              hipStream_t stream) {
    const float* x    = (const float*)d_in[0];
    const int*   ei   = (const int*)d_in[1];
    const float* W0   = (const float*)d_in[2];
    const float* W1   = (const float*)d_in[4];
    const float* W2   = (const float*)d_in[6];
    const float* g0   = (const float*)d_in[8];
    const float* be0  = (const float*)d_in[9];
    const float* g1   = (const float*)d_in[10];
    const float* be1  = (const float*)d_in[11];
    const float* g2   = (const float*)d_in[12];
    const float* be2  = (const float*)d_in[13];
    const float* fc1w = (const float*)d_in[14];
    const float* fc1b = (const float*)d_in[15];
    const float* fc2w = (const float*)d_in[16];
    const float* fc2b = (const float*)d_in[17];

    const int N = in_sizes[0] / 128;
    const int E = in_sizes[1] / 2;
    const int* srcp = ei;
    const int* dstp = ei + E;
    const int NB = (N + 255) >> 8;  // 256-node buckets (<=512)

    char* ws = (char*)d_ws;
    size_t off = 0;
    auto alloc = [&](size_t bytes) -> void* {
        void* p = ws + off;
        off = (off + bytes + 255) & ~(size_t)255;
        return p;
    };
    int*      gate    = (int*)alloc(64 * 4);
    int*      gcur    = (int*)alloc(512 * 4);
    float*    stats   = (float*)alloc(3 * 8 * 128 * 4);  // 3 layers x 8 replicas
    float*    dis     = (float*)alloc((size_t)N * 4);
    int*      row_ptr = (int*)alloc((size_t)(N + 1) * 4);
    unsigned* rec     = (unsigned*)alloc((size_t)NB * BUCK_CAP * 4);
    int*      ssrc    = (int*)alloc((size_t)E * 4);
    __half*   B0      = (__half*)alloc((size_t)N * 64 * 2);  // Hp fp16
    __half*   B1      = (__half*)alloc((size_t)N * 64 * 2);  // AGG fp16

    // CSR build (k_part self-initializes gcur/stats via gate)
    k_part<<<(E + PB_EDGES - 1) / PB_EDGES, 512, 0, stream>>>(
        srcp, dstp, gcur, stats, gate, rec, E, NB);
    k_bscat<<<NB, 256, 0, stream>>>(gcur, rec, dis, row_ptr, ssrc, gate, N, NB, E);

    const int gemm_grid = (N + 63) / 64;

    // Layer 0 (K=128, fp32 X, no BN)
    k_gemm<128, false, false><<<gemm_grid, 256, 0, stream>>>(x, W0, dis, nullptr, nullptr, nullptr, B0, N);
    k_gather<<<2048, 256, 0, stream>>>(row_ptr, ssrc, dis, (const uint4*)B0, (uint4*)B1, stats + 0, N);

    // Layer 1 (K=64, fp16 X, BN0 fused)
    k_gemm<64, true, true><<<gemm_grid, 256, 0, stream>>>(B1, W1, dis, stats + 0, g0, be0, B0, N);
    k_gather<<<2048, 256, 0, stream>>>(row_ptr, ssrc, dis, (const uint4*)B0, (uint4*)B1, stats + 1024, N);

    // Layer 2 (K=64, fp16 X, BN1 fused)
    k_gemm<64, true, true><<<gemm_grid, 256, 0, stream>>>(B1, W2, dis, stats + 1024, g1, be1, B0, N);
    k_gather<<<2048, 256, 0, stream>>>(row_ptr, ssrc, dis, (const uint4*)B0, (uint4*)B1, stats + 2048, N);

    // Head (BN2 fused)
    k_head<<<(N + 255) / 256, 256, 0, stream>>>((const uint2*)B1, stats + 2048, g2, be2,
                                                fc1w, fc1b, fc2w, fc2b,
                                                (float*)d_out, N);
}